// Round 1
// baseline (7810.928 us; speedup 1.0000x reference)
//
#include <hip/hip_runtime.h>
#include <hip/hip_bf16.h>

// MultiSpeciesResistanceModel: R_ij = Ainv_ii + Ainv_jj - 2 Ainv_ij where
// A = L + 11^T/n (SPD).  pinv's J/n correction cancels in R exactly.
// Pipeline: MLP -> assemble A -> blocked Cholesky (NB=64) -> W = G^{-1} by
// recursive block doubling -> Ainv = W^T W (compact lower tiles) -> R.
//
// Workspace layout (floats), required ws_size >= 50,855,936 bytes:
//   Mc   : 2080 lower tiles * 4096           = 8,519,680
//   U    : union { cond(131072) -> GinvAll(262144) -> T(4,194,304) -> diag(4096) }
// A/G/W live in d_out[0 .. 16.7M) (the R region) until final_R overwrites it.

#define NN 4096
#define LDA 4096
#define NEDGE 131072
#define INVN (1.0f/4096.0f)

// ---------------- edge MLPs ----------------
__device__ __forceinline__ float mlp_eval(const float* __restrict__ w,
                                          const float* __restrict__ x) {
  float h1[32], h2[32];
#pragma unroll
  for (int o = 0; o < 32; o += 4) {
    float4 s = *(const float4*)&w[512 + o];
#pragma unroll
    for (int i = 0; i < 16; ++i) {
      float4 wv = *(const float4*)&w[i * 32 + o];
      s.x = fmaf(x[i], wv.x, s.x); s.y = fmaf(x[i], wv.y, s.y);
      s.z = fmaf(x[i], wv.z, s.z); s.w = fmaf(x[i], wv.w, s.w);
    }
    h1[o] = fmaxf(s.x, 0.f); h1[o+1] = fmaxf(s.y, 0.f);
    h1[o+2] = fmaxf(s.z, 0.f); h1[o+3] = fmaxf(s.w, 0.f);
  }
#pragma unroll
  for (int o = 0; o < 32; o += 4) {
    float4 s = *(const float4*)&w[1568 + o];
#pragma unroll
    for (int i = 0; i < 32; ++i) {
      float4 wv = *(const float4*)&w[544 + i * 32 + o];
      s.x = fmaf(h1[i], wv.x, s.x); s.y = fmaf(h1[i], wv.y, s.y);
      s.z = fmaf(h1[i], wv.z, s.z); s.w = fmaf(h1[i], wv.w, s.w);
    }
    h2[o] = fmaxf(s.x, 0.f); h2[o+1] = fmaxf(s.y, 0.f);
    h2[o+2] = fmaxf(s.z, 0.f); h2[o+3] = fmaxf(s.w, 0.f);
  }
  float out = w[1632];
#pragma unroll
  for (int i = 0; i < 32; ++i) out = fmaf(h2[i], w[1600 + i], out);
  return out;
}

__global__ __launch_bounds__(256) void mlp_kernel(
    const float* __restrict__ ef,
    const float* __restrict__ sW1, const float* __restrict__ sb1,
    const float* __restrict__ sW2, const float* __restrict__ sb2,
    const float* __restrict__ sW3, const float* __restrict__ sb3,
    const float* __restrict__ pW1, const float* __restrict__ pb1,
    const float* __restrict__ pW2, const float* __restrict__ pb2,
    const float* __restrict__ pW3, const float* __restrict__ pb3,
    float* __restrict__ outS, float* __restrict__ outP,
    float* __restrict__ cond) {
  __shared__ float w[3328];  // shared net @0, species net @1664 (16B aligned)
  int t = threadIdx.x;
  for (int i = t; i < 512; i += 256) { w[i] = sW1[i]; w[1664 + i] = pW1[i]; }
  for (int i = t; i < 1024; i += 256) { w[544 + i] = sW2[i]; w[1664 + 544 + i] = pW2[i]; }
  if (t < 32) {
    w[512 + t] = sb1[t]; w[1568 + t] = sb2[t]; w[1600 + t] = sW3[t];
    w[1664 + 512 + t] = pb1[t]; w[1664 + 1568 + t] = pb2[t]; w[1664 + 1600 + t] = pW3[t];
  }
  if (t == 0) { w[1632] = sb3[0]; w[1664 + 1632] = pb3[0]; }
  __syncthreads();
  int e = blockIdx.x * 256 + t;
  float x[16];
#pragma unroll
  for (int i = 0; i < 16; i += 4) {
    float4 v = *(const float4*)&ef[(size_t)e * 16 + i];
    x[i] = v.x; x[i+1] = v.y; x[i+2] = v.z; x[i+3] = v.w;
  }
  float s = mlp_eval(w, x);
  float p = mlp_eval(w + 1664, x);
  outS[e] = s; outP[e] = p;
  float z = s + p;
  float sp = fmaxf(z, 0.f) + log1pf(expf(-fabsf(z)));  // jax.nn.softplus formula
  cond[e] = 1.0f / (sp + 1e-4f);
}

// ---------------- A = J/n, then Laplacian scatter ----------------
__global__ __launch_bounds__(256) void init_A(float* __restrict__ A) {
  size_t q = (size_t)blockIdx.x * 256 + threadIdx.x;  // float4 index
  *(float4*)&A[q * 4] = make_float4(INVN, INVN, INVN, INVN);
}

__global__ __launch_bounds__(256) void scatter_kernel(const int* __restrict__ ei,
                                                      const float* __restrict__ cond,
                                                      float* __restrict__ A) {
  int e = blockIdx.x * 256 + threadIdx.x;
  int i = ei[2 * e], j = ei[2 * e + 1];
  float c = cond[e];
  atomicAdd(&A[(size_t)i * (LDA + 1)], c);
  atomicAdd(&A[(size_t)j * (LDA + 1)], c);
  atomicAdd(&A[(size_t)i * LDA + j], -c);
  atomicAdd(&A[(size_t)j * LDA + i], -c);
}

// ---------------- fused 64x64 diag-block Cholesky + inverse ----------------
__global__ __launch_bounds__(256) void potf2_inv64(float* __restrict__ A, int k,
                                                   float* __restrict__ GinvAll) {
  __shared__ float sG[64][65];
  __shared__ float sX[64][65];
  __shared__ float sD[64];
  int t = threadIdx.x;
  float* blk = A + (size_t)k * 64 * (LDA + 1);
  for (int q = t; q < 4096; q += 256) {
    int r = q >> 6, c = q & 63;
    sG[r][c] = (c <= r) ? blk[(size_t)r * LDA + c] : 0.0f;
    sX[r][c] = (r == c) ? 1.0f : 0.0f;
  }
  __syncthreads();
  for (int j = 0; j < 64; ++j) {
    float dj = sqrtf(sG[j][j]);   // finalized by prior iter's barrier
    float inv = 1.0f / dj;
    if (t == 0) sD[j] = dj;       // defer diag write to avoid read/write race
    for (int i = j + 1 + t; i < 64; i += 256) sG[i][j] *= inv;
    for (int c = t; c <= j; c += 256) sX[j][c] *= inv;
    __syncthreads();
    int w = 63 - j;
    for (int q = t; q < w * w; q += 256) {          // trailing (square; upper junk ok)
      int i = j + 1 + q / w, p = j + 1 + q % w;
      sG[i][p] -= sG[i][j] * sG[p][j];
    }
    int jp1 = j + 1;
    for (int q = t; q < w * jp1; q += 256) {        // forward-subst update of X
      int i = j + 1 + q / jp1, c = q % jp1;
      sX[i][c] -= sG[i][j] * sX[j][c];
    }
    __syncthreads();
  }
  if (t < 64) sG[t][t] = sD[t];
  __syncthreads();
  float* Gk = GinvAll + (size_t)k * 4096;
  for (int q = t; q < 4096; q += 256) {
    int r = q >> 6, c = q & 63;
    if (c <= r) blk[(size_t)r * LDA + c] = sG[r][c];
    Gk[q] = sX[r][c];  // full 64x64, upper zeros included
  }
}

// ---------------- generic 64x64-tile fp32 GEMM ----------------
// C = beta?C:0 + alpha * op(A) * op(B);  !TA: A[m][k], TA: A[k][m];
// TB: B[n][k] (i.e. A*B^T), !TB: B[k][n].  M,N,K multiples of 64/16.
template <bool TA, bool TB, bool ACCUM, bool LOWER, bool KST, bool CCOMP>
__global__ __launch_bounds__(256) void gemm64(
    const float* __restrict__ Ab, long long aZ, int lda,
    const float* __restrict__ Bb, long long bZ, int ldb,
    float* __restrict__ Cb, long long cZ, int ldc, int K, float alpha) {
  int ti = blockIdx.x, tj = blockIdx.y;
  if (LOWER && tj > ti) return;
  const float* A = Ab + (long long)blockIdx.z * aZ;
  const float* B = Bb + (long long)blockIdx.z * bZ;
  __shared__ float As[16][68], Bs[16][68];
  int tid = threadIdx.x;
  int tx = tid & 15, ty = tid >> 4;
  float acc[4][4] = {};
  int m0 = ti * 64, n0 = tj * 64;
  int k0 = KST ? ti * 64 : 0;
  for (int k = k0; k < K; k += 16) {
    if (!TA) {
      int r = tid >> 2, c4 = (tid & 3) * 4;
      float4 v = *(const float4*)&A[(size_t)(m0 + r) * lda + k + c4];
      As[c4 + 0][r] = v.x; As[c4 + 1][r] = v.y; As[c4 + 2][r] = v.z; As[c4 + 3][r] = v.w;
    } else {
      int r = tid >> 4, c4 = (tid & 15) * 4;
      *(float4*)&As[r][c4] = *(const float4*)&A[(size_t)(k + r) * lda + m0 + c4];
    }
    if (TB) {
      int r = tid >> 2, c4 = (tid & 3) * 4;
      float4 v = *(const float4*)&B[(size_t)(n0 + r) * ldb + k + c4];
      Bs[c4 + 0][r] = v.x; Bs[c4 + 1][r] = v.y; Bs[c4 + 2][r] = v.z; Bs[c4 + 3][r] = v.w;
    } else {
      int r = tid >> 4, c4 = (tid & 15) * 4;
      *(float4*)&Bs[r][c4] = *(const float4*)&B[(size_t)(k + r) * ldb + n0 + c4];
    }
    __syncthreads();
#pragma unroll
    for (int kk = 0; kk < 16; ++kk) {
      float4 av = *(const float4*)&As[kk][ty * 4];
      float4 bv = *(const float4*)&Bs[kk][tx * 4];
      float a[4] = {av.x, av.y, av.z, av.w};
      float b[4] = {bv.x, bv.y, bv.z, bv.w};
#pragma unroll
      for (int i = 0; i < 4; ++i)
#pragma unroll
        for (int jj = 0; jj < 4; ++jj) acc[i][jj] = fmaf(a[i], b[jj], acc[i][jj]);
    }
    __syncthreads();
  }
  if (CCOMP) {  // compact lower-tile storage: tile q = ti(ti+1)/2+tj, 64x64
    float* C = Cb + ((size_t)ti * (ti + 1) / 2 + tj) * 4096;
#pragma unroll
    for (int i = 0; i < 4; ++i) {
      float4 c;
      c.x = alpha * acc[i][0]; c.y = alpha * acc[i][1];
      c.z = alpha * acc[i][2]; c.w = alpha * acc[i][3];
      *(float4*)&C[(ty * 4 + i) * 64 + tx * 4] = c;
    }
  } else {
    float* C = Cb + (long long)blockIdx.z * cZ;
#pragma unroll
    for (int i = 0; i < 4; ++i) {
      size_t off = (size_t)(m0 + ty * 4 + i) * ldc + n0 + tx * 4;
      float4 c;
      if (ACCUM) {
        c = *(float4*)&C[off];
        c.x += alpha * acc[i][0]; c.y += alpha * acc[i][1];
        c.z += alpha * acc[i][2]; c.w += alpha * acc[i][3];
      } else {
        c.x = alpha * acc[i][0]; c.y = alpha * acc[i][1];
        c.z = alpha * acc[i][2]; c.w = alpha * acc[i][3];
      }
      *(float4*)&C[off] = c;
    }
  }
}

// ---------------- zero strict upper + put Ginv blocks on diagonal ----------------
__global__ __launch_bounds__(256) void finish_W_prep(float* __restrict__ A,
                                                     const float* __restrict__ GinvAll) {
  size_t q = (size_t)blockIdx.x * 256 + threadIdx.x;  // float4 index
  int r = (int)(q >> 10), c4 = (int)(q & 1023) << 2;
  int rb = r >> 6, cb = c4 >> 6;
  if (cb == rb) {
    const float* g = GinvAll + (size_t)rb * 4096 + (size_t)(r & 63) * 64 + (c4 & 63);
    *(float4*)&A[q * 4] = *(const float4*)g;  // Ginv upper is already zero
  } else if (cb > rb) {
    *(float4*)&A[q * 4] = make_float4(0.f, 0.f, 0.f, 0.f);
  }  // strictly-lower off-diag blocks keep G
}

// ---------------- diag + final R ----------------
__global__ __launch_bounds__(256) void copy_diag(const float* __restrict__ Mc,
                                                 float* __restrict__ d) {
  int i = blockIdx.x * 256 + threadIdx.x;
  int tb = i >> 6;
  size_t q = (size_t)tb * (tb + 1) / 2 + tb;
  d[i] = Mc[q * 4096 + (size_t)(i & 63) * 65];
}

__global__ __launch_bounds__(256) void final_R(const float* __restrict__ Mc,
                                               const float* __restrict__ d,
                                               float* __restrict__ out) {
  size_t idx = (size_t)blockIdx.x * 256 + threadIdx.x;
  int r = (int)(idx >> 12), c = (int)(idx & 4095);
  int a = r > c ? r : c, b = r > c ? c : r;
  int ta = a >> 6, tb = b >> 6;
  size_t q = (size_t)ta * (ta + 1) / 2 + tb;
  float m = Mc[q * 4096 + (size_t)(a & 63) * 64 + (b & 63)];
  out[idx] = d[r] + d[c] - 2.0f * m;
}

// ---------------- launch ----------------
extern "C" void kernel_launch(void* const* d_in, const int* in_sizes, int n_in,
                              void* d_out, int out_size, void* d_ws, size_t ws_size,
                              hipStream_t stream) {
  const int* eidx = (const int*)d_in[1];
  const float* ef = (const float*)d_in[2];
  const float* sW1 = (const float*)d_in[4],  *sb1 = (const float*)d_in[5];
  const float* sW2 = (const float*)d_in[6],  *sb2 = (const float*)d_in[7];
  const float* sW3 = (const float*)d_in[8],  *sb3 = (const float*)d_in[9];
  const float* pW1 = (const float*)d_in[10], *pb1 = (const float*)d_in[11];
  const float* pW2 = (const float*)d_in[12], *pb2 = (const float*)d_in[13];
  const float* pW3 = (const float*)d_in[14], *pb3 = (const float*)d_in[15];

  float* dout = (float*)d_out;
  float* dA = dout;                       // A/G/W scribble space = R region
  float* outS = dout + (size_t)NN * NN;   // shared (131072)
  float* outP = outS + NEDGE;             // species (131072)

  float* ws = (float*)d_ws;
  float* Mc = ws;                         // 2080 * 4096 floats
  float* U = ws + 8519680ull;             // union region (4,194,304 floats)
  float* cond = U;                        // live: mlp -> scatter
  float* Ginv = U;                        // live: chol -> finish_W_prep
  float* Tbuf = U;                        // live: doubling
  float* diagb = U;                       // live: copy_diag -> final_R

  mlp_kernel<<<NEDGE / 256, 256, 0, stream>>>(ef, sW1, sb1, sW2, sb2, sW3, sb3,
                                              pW1, pb1, pW2, pb2, pW3, pb3,
                                              outS, outP, cond);
  init_A<<<(NN * NN / 4) / 256, 256, 0, stream>>>(dA);
  scatter_kernel<<<NEDGE / 256, 256, 0, stream>>>(eidx, cond, dA);

  // blocked Cholesky, NB = 64
  for (int k = 0; k < NN / 64; ++k) {
    potf2_inv64<<<1, 256, 0, stream>>>(dA, k, Ginv);
    int rem = NN - (k + 1) * 64;
    if (rem > 0) {
      float* panel = dA + (size_t)(k + 1) * 64 * LDA + (size_t)k * 64;
      // L21 = A21 * Ginv^T  (in-place; each WG owns its full 64-row strip)
      gemm64<false, true, false, false, false, false>
          <<<dim3(rem / 64, 1, 1), 256, 0, stream>>>(
              panel, 0, LDA, Ginv + (size_t)k * 4096, 0, 64, panel, 0, LDA, 64, 1.0f);
      float* trail = dA + (size_t)(k + 1) * 64 * (LDA + 1);
      // trailing SYRK (lower tiles): C -= L21 * L21^T
      gemm64<false, true, true, true, false, false>
          <<<dim3(rem / 64, rem / 64, 1), 256, 0, stream>>>(
              panel, 0, LDA, panel, 0, LDA, trail, 0, LDA, 64, -1.0f);
    }
  }

  finish_W_prep<<<(NN * NN / 4) / 256, 256, 0, stream>>>(dA, Ginv);

  // W = G^{-1} by recursive doubling: W21 = -W22 * (L21 * W11)
  for (int S = 64; S <= 2048; S *= 2) {
    int np = NN / (2 * S);
    long long pz = (long long)2 * S * (LDA + 1);
    gemm64<false, false, false, false, false, false>
        <<<dim3(S / 64, S / 64, np), 256, 0, stream>>>(
            dA + (size_t)S * LDA, pz, LDA,   // L21
            dA, pz, LDA,                     // W11
            Tbuf, (long long)S * S, S, S, 1.0f);
    gemm64<false, false, false, false, false, false>
        <<<dim3(S / 64, S / 64, np), 256, 0, stream>>>(
            dA + (size_t)S * (LDA + 1), pz, LDA,  // W22
            Tbuf, (long long)S * S, S,            // T
            dA + (size_t)S * LDA, pz, LDA, S, -1.0f);
  }

  // Ainv = W^T W into compact lower tiles (K starts at ti*64: W[p][r]=0 for p<r)
  gemm64<true, false, false, true, true, true>
      <<<dim3(64, 64, 1), 256, 0, stream>>>(dA, 0, LDA, dA, 0, LDA, Mc, 0, 64,
                                            NN, 1.0f);

  copy_diag<<<NN / 256, 256, 0, stream>>>(Mc, diagb);
  final_R<<<(NN * NN) / 256, 256, 0, stream>>>(Mc, diagb, dout);
}

// Round 2
// 5160.418 us; speedup vs baseline: 1.5136x; 1.5136x over previous
//
#include <hip/hip_runtime.h>
#include <hip/hip_bf16.h>

// MultiSpeciesResistanceModel: R_ij = Ainv_ii + Ainv_jj - 2 Ainv_ij where
// A = L + 11^T/n (SPD).  pinv's J/n correction cancels in R exactly.
// Pipeline: MLP -> assemble A -> blocked Cholesky (NB=64, wave-level potf2)
// -> W = G^{-1} by recursive block doubling -> Ainv = W^T W (compact lower
// tiles) -> R.
//
// Workspace layout (floats), required ws_size >= 50,855,936 bytes:
//   Mc   : 2080 lower tiles * 4096           = 8,519,680
//   U    : union { cond(131072) -> GinvAll(262144) -> T(4,194,304) -> diag(4096) }
// A/G/W live in d_out[0 .. 16.7M) (the R region) until final_R overwrites it.

#define NN 4096
#define LDA 4096
#define NEDGE 131072
#define INVN (1.0f/4096.0f)

// ---------------- edge MLPs ----------------
__device__ __forceinline__ float mlp_eval(const float* __restrict__ w,
                                          const float* __restrict__ x) {
  float h1[32], h2[32];
#pragma unroll
  for (int o = 0; o < 32; o += 4) {
    float4 s = *(const float4*)&w[512 + o];
#pragma unroll
    for (int i = 0; i < 16; ++i) {
      float4 wv = *(const float4*)&w[i * 32 + o];
      s.x = fmaf(x[i], wv.x, s.x); s.y = fmaf(x[i], wv.y, s.y);
      s.z = fmaf(x[i], wv.z, s.z); s.w = fmaf(x[i], wv.w, s.w);
    }
    h1[o] = fmaxf(s.x, 0.f); h1[o+1] = fmaxf(s.y, 0.f);
    h1[o+2] = fmaxf(s.z, 0.f); h1[o+3] = fmaxf(s.w, 0.f);
  }
#pragma unroll
  for (int o = 0; o < 32; o += 4) {
    float4 s = *(const float4*)&w[1568 + o];
#pragma unroll
    for (int i = 0; i < 32; ++i) {
      float4 wv = *(const float4*)&w[544 + i * 32 + o];
      s.x = fmaf(h1[i], wv.x, s.x); s.y = fmaf(h1[i], wv.y, s.y);
      s.z = fmaf(h1[i], wv.z, s.z); s.w = fmaf(h1[i], wv.w, s.w);
    }
    h2[o] = fmaxf(s.x, 0.f); h2[o+1] = fmaxf(s.y, 0.f);
    h2[o+2] = fmaxf(s.z, 0.f); h2[o+3] = fmaxf(s.w, 0.f);
  }
  float out = w[1632];
#pragma unroll
  for (int i = 0; i < 32; ++i) out = fmaf(h2[i], w[1600 + i], out);
  return out;
}

__global__ __launch_bounds__(256) void mlp_kernel(
    const float* __restrict__ ef,
    const float* __restrict__ sW1, const float* __restrict__ sb1,
    const float* __restrict__ sW2, const float* __restrict__ sb2,
    const float* __restrict__ sW3, const float* __restrict__ sb3,
    const float* __restrict__ pW1, const float* __restrict__ pb1,
    const float* __restrict__ pW2, const float* __restrict__ pb2,
    const float* __restrict__ pW3, const float* __restrict__ pb3,
    float* __restrict__ outS, float* __restrict__ outP,
    float* __restrict__ cond) {
  __shared__ float w[3328];  // shared net @0, species net @1664 (16B aligned)
  int t = threadIdx.x;
  for (int i = t; i < 512; i += 256) { w[i] = sW1[i]; w[1664 + i] = pW1[i]; }
  for (int i = t; i < 1024; i += 256) { w[544 + i] = sW2[i]; w[1664 + 544 + i] = pW2[i]; }
  if (t < 32) {
    w[512 + t] = sb1[t]; w[1568 + t] = sb2[t]; w[1600 + t] = sW3[t];
    w[1664 + 512 + t] = pb1[t]; w[1664 + 1568 + t] = pb2[t]; w[1664 + 1600 + t] = pW3[t];
  }
  if (t == 0) { w[1632] = sb3[0]; w[1664 + 1632] = pb3[0]; }
  __syncthreads();
  int e = blockIdx.x * 256 + t;
  float x[16];
#pragma unroll
  for (int i = 0; i < 16; i += 4) {
    float4 v = *(const float4*)&ef[(size_t)e * 16 + i];
    x[i] = v.x; x[i+1] = v.y; x[i+2] = v.z; x[i+3] = v.w;
  }
  float s = mlp_eval(w, x);
  float p = mlp_eval(w + 1664, x);
  outS[e] = s; outP[e] = p;
  float z = s + p;
  float sp = fmaxf(z, 0.f) + log1pf(expf(-fabsf(z)));  // jax.nn.softplus formula
  cond[e] = 1.0f / (sp + 1e-4f);
}

// ---------------- A = J/n, then Laplacian scatter ----------------
__global__ __launch_bounds__(256) void init_A(float* __restrict__ A) {
  size_t q = (size_t)blockIdx.x * 256 + threadIdx.x;  // float4 index
  *(float4*)&A[q * 4] = make_float4(INVN, INVN, INVN, INVN);
}

__global__ __launch_bounds__(256) void scatter_kernel(const int* __restrict__ ei,
                                                      const float* __restrict__ cond,
                                                      float* __restrict__ A) {
  int e = blockIdx.x * 256 + threadIdx.x;
  int i = ei[2 * e], j = ei[2 * e + 1];
  float c = cond[e];
  atomicAdd(&A[(size_t)i * (LDA + 1)], c);
  atomicAdd(&A[(size_t)j * (LDA + 1)], c);
  atomicAdd(&A[(size_t)i * LDA + j], -c);
  atomicAdd(&A[(size_t)j * LDA + i], -c);
}

// ---------------- single-wave 64x64 diag Cholesky + inverse ----------------
// Lane i holds row i of the block (a[]) and row i of X = L11^{-1} (x[]) in
// registers; pivot broadcasts via v_readlane (no LDS, no barriers).
__device__ __forceinline__ float rlane(float v, int l) {
  return __int_as_float(__builtin_amdgcn_readlane(__float_as_int(v), l));
}

__global__ __launch_bounds__(64) void potf2_wave(float* __restrict__ A, int k,
                                                 float* __restrict__ GinvAll) {
  float* blk = A + (size_t)k * 64 * (LDA + 1);
  const int lane = threadIdx.x;
  float a[64], x[64];
#pragma unroll
  for (int c = 0; c < 64; c += 4) {
    float4 v = *(const float4*)&blk[(size_t)lane * LDA + c];
    a[c] = v.x; a[c+1] = v.y; a[c+2] = v.z; a[c+3] = v.w;
    x[c]   = (c   == lane) ? 1.f : 0.f;
    x[c+1] = (c+1 == lane) ? 1.f : 0.f;
    x[c+2] = (c+2 == lane) ? 1.f : 0.f;
    x[c+3] = (c+3 == lane) ? 1.f : 0.f;
  }
#pragma unroll
  for (int j = 0; j < 64; ++j) {
    float dj = rlane(a[j], j);
    float inv = 1.0f / sqrtf(dj);
    float lij = a[j] * inv;   // lane i>j: L[i][j]; lane j: L[j][j]=sqrt(dj)
    a[j] = lij;               // lanes i<j write junk into masked upper region
    float coefT = -lij;
    float sX = (lane == j) ? inv : 1.0f;
    float coefX = (lane > j) ? -lij : 0.0f;
    // trailing update: a[i][c] -= L[i][j]*L[c][j]  (junk rows harmless)
#pragma unroll
    for (int c = j + 1; c < 64; ++c)
      a[c] = fmaf(coefT, rlane(lij, c), a[c]);
    // X forward substitution: row j scales by inv; rows i>j subtract
#pragma unroll
    for (int c = 0; c <= j; ++c) {
      float xjc = rlane(x[c], j) * inv;
      x[c] = fmaf(coefX, xjc, x[c] * sX);
    }
  }
  float* Gk = GinvAll + (size_t)k * 4096;
#pragma unroll
  for (int c = 0; c < 64; c += 4) {
    *(float4*)&blk[(size_t)lane * LDA + c] = make_float4(a[c], a[c+1], a[c+2], a[c+3]);
    *(float4*)&Gk[lane * 64 + c] = make_float4(x[c], x[c+1], x[c+2], x[c+3]);
  }
}

// ---------------- generic 64x64-tile fp32 GEMM ----------------
template <bool TA, bool TB, bool ACCUM, bool LOWER, bool KST, bool CCOMP>
__global__ __launch_bounds__(256) void gemm64(
    const float* __restrict__ Ab, long long aZ, int lda,
    const float* __restrict__ Bb, long long bZ, int ldb,
    float* __restrict__ Cb, long long cZ, int ldc, int K, float alpha) {
  int ti = blockIdx.x, tj = blockIdx.y;
  if (LOWER && tj > ti) return;
  const float* A = Ab + (long long)blockIdx.z * aZ;
  const float* B = Bb + (long long)blockIdx.z * bZ;
  __shared__ float As[16][68], Bs[16][68];
  int tid = threadIdx.x;
  int tx = tid & 15, ty = tid >> 4;
  float acc[4][4] = {};
  int m0 = ti * 64, n0 = tj * 64;
  int k0 = KST ? ti * 64 : 0;
  for (int k = k0; k < K; k += 16) {
    if (!TA) {
      int r = tid >> 2, c4 = (tid & 3) * 4;
      float4 v = *(const float4*)&A[(size_t)(m0 + r) * lda + k + c4];
      As[c4 + 0][r] = v.x; As[c4 + 1][r] = v.y; As[c4 + 2][r] = v.z; As[c4 + 3][r] = v.w;
    } else {
      int r = tid >> 4, c4 = (tid & 15) * 4;
      *(float4*)&As[r][c4] = *(const float4*)&A[(size_t)(k + r) * lda + m0 + c4];
    }
    if (TB) {
      int r = tid >> 2, c4 = (tid & 3) * 4;
      float4 v = *(const float4*)&B[(size_t)(n0 + r) * ldb + k + c4];
      Bs[c4 + 0][r] = v.x; Bs[c4 + 1][r] = v.y; Bs[c4 + 2][r] = v.z; Bs[c4 + 3][r] = v.w;
    } else {
      int r = tid >> 4, c4 = (tid & 15) * 4;
      *(float4*)&Bs[r][c4] = *(const float4*)&B[(size_t)(k + r) * ldb + n0 + c4];
    }
    __syncthreads();
#pragma unroll
    for (int kk = 0; kk < 16; ++kk) {
      float4 av = *(const float4*)&As[kk][ty * 4];
      float4 bv = *(const float4*)&Bs[kk][tx * 4];
      float a[4] = {av.x, av.y, av.z, av.w};
      float b[4] = {bv.x, bv.y, bv.z, bv.w};
#pragma unroll
      for (int i = 0; i < 4; ++i)
#pragma unroll
        for (int jj = 0; jj < 4; ++jj) acc[i][jj] = fmaf(a[i], b[jj], acc[i][jj]);
    }
    __syncthreads();
  }
  if (CCOMP) {
    float* C = Cb + ((size_t)ti * (ti + 1) / 2 + tj) * 4096;
#pragma unroll
    for (int i = 0; i < 4; ++i) {
      float4 c;
      c.x = alpha * acc[i][0]; c.y = alpha * acc[i][1];
      c.z = alpha * acc[i][2]; c.w = alpha * acc[i][3];
      *(float4*)&C[(ty * 4 + i) * 64 + tx * 4] = c;
    }
  } else {
    float* C = Cb + (long long)blockIdx.z * cZ;
#pragma unroll
    for (int i = 0; i < 4; ++i) {
      size_t off = (size_t)(m0 + ty * 4 + i) * ldc + n0 + tx * 4;
      float4 c;
      if (ACCUM) {
        c = *(float4*)&C[off];
        c.x += alpha * acc[i][0]; c.y += alpha * acc[i][1];
        c.z += alpha * acc[i][2]; c.w += alpha * acc[i][3];
      } else {
        c.x = alpha * acc[i][0]; c.y = alpha * acc[i][1];
        c.z = alpha * acc[i][2]; c.w = alpha * acc[i][3];
      }
      *(float4*)&C[off] = c;
    }
  }
}

// ---------------- 128x128-tile fp32 GEMM, 8x8 micro ----------------
// C = alpha * op(A) * B.  TA: A[k][m] else A[m][k]; B always B[k][n].
// CCOMP: write into compact 64x64 lower tiles (Mc), sub-tile masked.
template <bool TA, bool LOWER, bool KST, bool CCOMP>
__global__ __launch_bounds__(256) void gemm128(
    const float* __restrict__ Ab, long long aZ, int lda,
    const float* __restrict__ Bb, long long bZ, int ldb,
    float* __restrict__ Cb, long long cZ, int ldc, int K, float alpha) {
  int ti = blockIdx.x, tj = blockIdx.y;
  if (LOWER && tj > ti) return;
  const float* A = Ab + (long long)blockIdx.z * aZ;
  const float* B = Bb + (long long)blockIdx.z * bZ;
  __shared__ float As[16][132], Bs[16][132];
  int tid = threadIdx.x;
  int tx = tid & 15, ty = tid >> 4;
  float acc[8][8] = {};
  int m0 = ti * 128, n0 = tj * 128;
  int k0 = KST ? ti * 128 : 0;
  for (int k = k0; k < K; k += 16) {
    if (!TA) {
      int r = tid >> 1, c8 = (tid & 1) * 8;
      const float* src = &A[(size_t)(m0 + r) * lda + k + c8];
      float4 v0 = *(const float4*)src;
      float4 v1 = *(const float4*)(src + 4);
      As[c8 + 0][r] = v0.x; As[c8 + 1][r] = v0.y; As[c8 + 2][r] = v0.z; As[c8 + 3][r] = v0.w;
      As[c8 + 4][r] = v1.x; As[c8 + 5][r] = v1.y; As[c8 + 6][r] = v1.z; As[c8 + 7][r] = v1.w;
    } else {
      int r = tid >> 4, c8 = (tid & 15) * 8;
      const float* src = &A[(size_t)(k + r) * lda + m0 + c8];
      *(float4*)&As[r][c8]     = *(const float4*)src;
      *(float4*)&As[r][c8 + 4] = *(const float4*)(src + 4);
    }
    {
      int r = tid >> 4, c8 = (tid & 15) * 8;
      const float* src = &B[(size_t)(k + r) * ldb + n0 + c8];
      *(float4*)&Bs[r][c8]     = *(const float4*)src;
      *(float4*)&Bs[r][c8 + 4] = *(const float4*)(src + 4);
    }
    __syncthreads();
#pragma unroll
    for (int kk = 0; kk < 16; ++kk) {
      float a8[8], b8[8];
      *(float4*)&a8[0] = *(const float4*)&As[kk][ty * 8];
      *(float4*)&a8[4] = *(const float4*)&As[kk][ty * 8 + 4];
      *(float4*)&b8[0] = *(const float4*)&Bs[kk][tx * 8];
      *(float4*)&b8[4] = *(const float4*)&Bs[kk][tx * 8 + 4];
#pragma unroll
      for (int i = 0; i < 8; ++i)
#pragma unroll
        for (int jj = 0; jj < 8; ++jj) acc[i][jj] = fmaf(a8[i], b8[jj], acc[i][jj]);
    }
    __syncthreads();
  }
  if (CCOMP) {
    int TI = 2 * ti + (ty >> 3), TJ = 2 * tj + (tx >> 3);
    if (TJ <= TI) {
      float* C = Cb + ((size_t)TI * (TI + 1) / 2 + TJ) * 4096;
      int rr = (ty & 7) * 8, cc = (tx & 7) * 8;
#pragma unroll
      for (int i = 0; i < 8; ++i) {
        float4 c0, c1;
        c0.x = alpha * acc[i][0]; c0.y = alpha * acc[i][1];
        c0.z = alpha * acc[i][2]; c0.w = alpha * acc[i][3];
        c1.x = alpha * acc[i][4]; c1.y = alpha * acc[i][5];
        c1.z = alpha * acc[i][6]; c1.w = alpha * acc[i][7];
        *(float4*)&C[(rr + i) * 64 + cc]     = c0;
        *(float4*)&C[(rr + i) * 64 + cc + 4] = c1;
      }
    }
  } else {
    float* C = Cb + (long long)blockIdx.z * cZ;
#pragma unroll
    for (int i = 0; i < 8; ++i) {
      float* dst = &C[(size_t)(m0 + ty * 8 + i) * ldc + n0 + tx * 8];
      float4 c0, c1;
      c0.x = alpha * acc[i][0]; c0.y = alpha * acc[i][1];
      c0.z = alpha * acc[i][2]; c0.w = alpha * acc[i][3];
      c1.x = alpha * acc[i][4]; c1.y = alpha * acc[i][5];
      c1.z = alpha * acc[i][6]; c1.w = alpha * acc[i][7];
      *(float4*)dst       = c0;
      *(float4*)(dst + 4) = c1;
    }
  }
}

// ---------------- zero strict upper + put Ginv blocks on diagonal ----------------
__global__ __launch_bounds__(256) void finish_W_prep(float* __restrict__ A,
                                                     const float* __restrict__ GinvAll) {
  size_t q = (size_t)blockIdx.x * 256 + threadIdx.x;  // float4 index
  int r = (int)(q >> 10), c4 = (int)(q & 1023) << 2;
  int rb = r >> 6, cb = c4 >> 6;
  if (cb == rb) {
    const float* g = GinvAll + (size_t)rb * 4096 + (size_t)(r & 63) * 64 + (c4 & 63);
    *(float4*)&A[q * 4] = *(const float4*)g;  // Ginv upper is already zero
  } else if (cb > rb) {
    *(float4*)&A[q * 4] = make_float4(0.f, 0.f, 0.f, 0.f);
  }  // strictly-lower off-diag blocks keep G
}

// ---------------- diag + final R ----------------
__global__ __launch_bounds__(256) void copy_diag(const float* __restrict__ Mc,
                                                 float* __restrict__ d) {
  int i = blockIdx.x * 256 + threadIdx.x;
  int tb = i >> 6;
  size_t q = (size_t)tb * (tb + 1) / 2 + tb;
  d[i] = Mc[q * 4096 + (size_t)(i & 63) * 65];
}

__global__ __launch_bounds__(256) void final_R(const float* __restrict__ Mc,
                                               const float* __restrict__ d,
                                               float* __restrict__ out) {
  size_t idx = (size_t)blockIdx.x * 256 + threadIdx.x;
  int r = (int)(idx >> 12), c = (int)(idx & 4095);
  int a = r > c ? r : c, b = r > c ? c : r;
  int ta = a >> 6, tb = b >> 6;
  size_t q = (size_t)ta * (ta + 1) / 2 + tb;
  float m = Mc[q * 4096 + (size_t)(a & 63) * 64 + (b & 63)];
  out[idx] = d[r] + d[c] - 2.0f * m;
}

// ---------------- launch ----------------
extern "C" void kernel_launch(void* const* d_in, const int* in_sizes, int n_in,
                              void* d_out, int out_size, void* d_ws, size_t ws_size,
                              hipStream_t stream) {
  const int* eidx = (const int*)d_in[1];
  const float* ef = (const float*)d_in[2];
  const float* sW1 = (const float*)d_in[4],  *sb1 = (const float*)d_in[5];
  const float* sW2 = (const float*)d_in[6],  *sb2 = (const float*)d_in[7];
  const float* sW3 = (const float*)d_in[8],  *sb3 = (const float*)d_in[9];
  const float* pW1 = (const float*)d_in[10], *pb1 = (const float*)d_in[11];
  const float* pW2 = (const float*)d_in[12], *pb2 = (const float*)d_in[13];
  const float* pW3 = (const float*)d_in[14], *pb3 = (const float*)d_in[15];

  float* dout = (float*)d_out;
  float* dA = dout;                       // A/G/W scribble space = R region
  float* outS = dout + (size_t)NN * NN;   // shared (131072)
  float* outP = outS + NEDGE;             // species (131072)

  float* ws = (float*)d_ws;
  float* Mc = ws;                         // 2080 * 4096 floats
  float* U = ws + 8519680ull;             // union region (4,194,304 floats)
  float* cond = U;                        // live: mlp -> scatter
  float* Ginv = U;                        // live: chol -> finish_W_prep
  float* Tbuf = U;                        // live: doubling
  float* diagb = U;                       // live: copy_diag -> final_R

  mlp_kernel<<<NEDGE / 256, 256, 0, stream>>>(ef, sW1, sb1, sW2, sb2, sW3, sb3,
                                              pW1, pb1, pW2, pb2, pW3, pb3,
                                              outS, outP, cond);
  init_A<<<(NN * NN / 4) / 256, 256, 0, stream>>>(dA);
  scatter_kernel<<<NEDGE / 256, 256, 0, stream>>>(eidx, cond, dA);

  // blocked Cholesky, NB = 64, wave-level diag factorization
  for (int k = 0; k < NN / 64; ++k) {
    potf2_wave<<<1, 64, 0, stream>>>(dA, k, Ginv);
    int rem = NN - (k + 1) * 64;
    if (rem > 0) {
      float* panel = dA + (size_t)(k + 1) * 64 * LDA + (size_t)k * 64;
      // L21 = A21 * Ginv^T  (in-place; each WG owns its full 64-row strip)
      gemm64<false, true, false, false, false, false>
          <<<dim3(rem / 64, 1, 1), 256, 0, stream>>>(
              panel, 0, LDA, Ginv + (size_t)k * 4096, 0, 64, panel, 0, LDA, 64, 1.0f);
      float* trail = dA + (size_t)(k + 1) * 64 * (LDA + 1);
      // trailing SYRK (lower tiles): C -= L21 * L21^T
      gemm64<false, true, true, true, false, false>
          <<<dim3(rem / 64, rem / 64, 1), 256, 0, stream>>>(
              panel, 0, LDA, panel, 0, LDA, trail, 0, LDA, 64, -1.0f);
    }
  }

  finish_W_prep<<<(NN * NN / 4) / 256, 256, 0, stream>>>(dA, Ginv);

  // W = G^{-1} by recursive doubling: W21 = -W22 * (L21 * W11)
  for (int S = 64; S <= 2048; S *= 2) {
    int np = NN / (2 * S);
    long long pz = (long long)2 * S * (LDA + 1);
    if (S == 64) {
      gemm64<false, false, false, false, false, false>
          <<<dim3(1, 1, np), 256, 0, stream>>>(
              dA + (size_t)S * LDA, pz, LDA, dA, pz, LDA,
              Tbuf, (long long)S * S, S, S, 1.0f);
      gemm64<false, false, false, false, false, false>
          <<<dim3(1, 1, np), 256, 0, stream>>>(
              dA + (size_t)S * (LDA + 1), pz, LDA, Tbuf, (long long)S * S, S,
              dA + (size_t)S * LDA, pz, LDA, S, -1.0f);
    } else {
      gemm128<false, false, false, false>
          <<<dim3(S / 128, S / 128, np), 256, 0, stream>>>(
              dA + (size_t)S * LDA, pz, LDA, dA, pz, LDA,
              Tbuf, (long long)S * S, S, S, 1.0f);
      gemm128<false, false, false, false>
          <<<dim3(S / 128, S / 128, np), 256, 0, stream>>>(
              dA + (size_t)S * (LDA + 1), pz, LDA, Tbuf, (long long)S * S, S,
              dA + (size_t)S * LDA, pz, LDA, S, -1.0f);
    }
  }

  // Ainv = W^T W into compact lower 64-tiles (K starts at ti*128: W[p][r]=0 for p<r)
  gemm128<true, true, true, true>
      <<<dim3(32, 32, 1), 256, 0, stream>>>(dA, 0, LDA, dA, 0, LDA, Mc, 0, 64,
                                            NN, 1.0f);

  copy_diag<<<NN / 256, 256, 0, stream>>>(Mc, diagb);
  final_R<<<(NN * NN) / 256, 256, 0, stream>>>(Mc, diagb, dout);
}